// Round 5
// baseline (496.656 us; speedup 1.0000x reference)
//
#include <hip/hip_runtime.h>
#include <math.h>

// DAM (dual attention) on MI355X — single fused kernel, hand-rolled grid barrier.
// B=2, C=32, N=4096, fp32 in/out; bf16 MFMA for the two N^2 passes.
//
// out = alpha*e_p + beta*e_c + 2*a
//   f = relu(BN(a));  cb[n,m] = sum_c f[c,n]f[c,m]
//   w[m,n] = exp(cb[m,n]-M[n]) / Z[n],  M[n]=cb[n,n] (shift-invariant stabilizer)
//   e_p[c,m] = sum_n f[c,n] w[m,n]
//   aa = a a^T (32x32 fp32), x = softmax over batch axis; e_c[i,n] = sum_j x[b,j,i] a[b,j,n]
//
// Grid barrier: 512 blocks x 256 thr, __launch_bounds__(256,2) => VGPR<=256,
// LDS 17.4KB => 2 blocks/CU guaranteed => all 512 co-resident (k x 256 recipe).

#define BB 2
#define CC 32
#define NN 4096
#define EPSV 1e-5f
#define NBLK 512

typedef short short8 __attribute__((ext_vector_type(8)));  // 8 bf16
typedef float f32x4 __attribute__((ext_vector_type(4)));

// ws float offsets
#define OFF_FNC  0          // bf16 f [B][N][C]      (131072 floats storage)
#define OFF_FCN  131072     // bf16 f [B][C][N]      (131072)
#define OFF_M    262144     // f32 M[b][n]           (8192)
#define OFF_SC   270336     // BN scale              (32)
#define OFF_SH   270368     // BN shift              (32)
#define OFF_XW   270400     // xw[b][i][j]=x[b,j,i]  (2048)
#define OFF_AAP  272448     // aa partials [b][16][32][32] (32768)
#define OFF_Z    305216     // f32 Z[b][n] atomic    (8192)
#define OFF_EP   313408     // f32 ep[b][c][n] atomic(262144)
#define OFF_CNT  575552     // barrier counter (zeroed by memsetAsync)
#define ZERO_BASE 305216
#define ZERO_N4   67584     // (8192+262144)/4 float4s

__device__ inline ushort f2bf(float x) {            // RNE f32->bf16
    uint u = __float_as_uint(x);
    uint r = u + 0x7FFFu + ((u >> 16) & 1u);
    return (ushort)(r >> 16);
}
__device__ inline float bf2f(ushort h) { return __uint_as_float(((uint)h) << 16); }
__device__ inline uint packbf(float lo, float hi) { // truncating pack (w>=0)
    return (__float_as_uint(hi) & 0xFFFF0000u) | (__float_as_uint(lo) >> 16);
}

// device-scope grid barrier (release-fence, count, spin, acquire-fence)
__device__ inline void gsync(uint* cnt, uint target) {
    __threadfence();                      // agent-scope release
    __syncthreads();
    if (threadIdx.x == 0) {
        atomicAdd(cnt, 1u);               // device-scope by default
        while (atomicAdd(cnt, 0u) < target) __builtin_amdgcn_s_sleep(1);
    }
    __syncthreads();
    __threadfence();                      // agent-scope acquire
}

__global__ void __launch_bounds__(256, 2)
k_dam(const float* __restrict__ x, const float* __restrict__ gamma,
      const float* __restrict__ bias, const float* __restrict__ alpha_p,
      const float* __restrict__ beta_p, float* __restrict__ ws,
      float* __restrict__ out) {
    __shared__ float smem[4352];   // 17 KB: aa tile 32x132 / P4 {sa 256, sxw 1056}
    const int blk = blockIdx.x, t = threadIdx.x;
    const int lane = t & 63, wv = t >> 6;
    const int ml = lane & 15, kg = lane >> 4;
    const f32x4 fzero = {0.f, 0.f, 0.f, 0.f};
    uint* cnt = (uint*)(ws + OFF_CNT);

    // ================= P0: BN stats | aa partials | zero Z+EP =================
    if (blk < 32) {
        const int c = blk;
        float s = 0.f, s2 = 0.f;
        for (int i = t; i < BB * NN; i += 256) {
            const int bb = i >> 12, n = i & (NN - 1);
            const float v = x[((size_t)(bb * CC + c)) * NN + n];
            s += v; s2 += v * v;
        }
        for (int off = 32; off; off >>= 1) { s += __shfl_down(s, off); s2 += __shfl_down(s2, off); }
        if (lane == 0) { smem[wv] = s; smem[4 + wv] = s2; }
        __syncthreads();
        if (t == 0) {
            const float S = smem[0] + smem[1] + smem[2] + smem[3];
            const float S2 = smem[4] + smem[5] + smem[6] + smem[7];
            const float mean = S * (1.f / (BB * NN));
            const float var = S2 * (1.f / (BB * NN)) - mean * mean;  // biased
            const float sc = gamma[c] * rsqrtf(var + EPSV);
            ws[OFF_SC + c] = sc;
            ws[OFF_SH + c] = bias[c] - mean * sc;
        }
    } else if (blk < 64) {
        // fp32 Gram partial over a 256-wide n-chunk (LDS-tiled, padded stride 132)
        const int blk2 = blk - 32;
        const int b = blk2 >> 4, chnk = blk2 & 15;
        const int nb = chnk * 256;
        const int d = t >> 3, cg4 = (t & 7) * 4;
        float a0 = 0.f, a1 = 0.f, a2 = 0.f, a3 = 0.f;
        for (int it = 0; it < 2; ++it) {
            __syncthreads();
            for (int li = t; li < 4096; li += 256) {
                const int row = li >> 7, col = li & 127;
                smem[row * 132 + col] = x[((size_t)(b * CC + row)) * NN + nb + it * 128 + col];
            }
            __syncthreads();
            for (int k = 0; k < 128; ++k) {
                const float vd = smem[d * 132 + k];
                a0 += smem[(cg4 + 0) * 132 + k] * vd;
                a1 += smem[(cg4 + 1) * 132 + k] * vd;
                a2 += smem[(cg4 + 2) * 132 + k] * vd;
                a3 += smem[(cg4 + 3) * 132 + k] * vd;
            }
        }
        float* dst = ws + OFF_AAP + ((size_t)((b * 16 + chnk) * CC + d)) * CC + cg4;
        dst[0] = a0; dst[1] = a1; dst[2] = a2; dst[3] = a3;
    } else {
        for (int gid = (blk - 64) * 256 + t; gid < ZERO_N4; gid += 448 * 256)
            ((float4*)(ws + ZERO_BASE))[gid] = make_float4(0.f, 0.f, 0.f, 0.f);
    }
    gsync(cnt, 1 * NBLK);

    // ====== P1: f = relu(bn(x)) -> bf16 (both layouts) + M; blk 511: xw ======
    {
        const int ch = t & 31;
        const float sc = ws[OFF_SC + ch], sh = ws[OFF_SH + ch];
        #pragma unroll
        for (int it = 0; it < 2; ++it) {
            const int col = (t >> 5) + it * 8;
            const int idx = blk * 16 + col;       // 8192 columns
            const int b = idx >> 12, n = idx & (NN - 1);
            const float v = x[((size_t)(b * CC + ch)) * NN + n];
            const float f = fmaxf(v * sc + sh, 0.f);
            const ushort h = f2bf(f);
            const float fr = bf2f(h);
            ((ushort*)(ws + OFF_FNC))[(size_t)idx * CC + ch] = h;
            ((ushort*)(ws + OFF_FCN))[((size_t)(b * CC + ch)) * NN + n] = h;
            float s = fr * fr;
            s += __shfl_xor(s, 1); s += __shfl_xor(s, 2); s += __shfl_xor(s, 4);
            s += __shfl_xor(s, 8); s += __shfl_xor(s, 16);
            if (ch == 0) ws[OFF_M + idx] = s;     // diag of bf16-cb, fp32 acc
        }
        if (blk == 511) {                         // CAM batch-axis softmax
            for (int li = t; li < CC * CC; li += 256) {
                const int i = li >> 5, j = li & 31;
                float q0 = 0.f, q1 = 0.f;
                for (int cchunk = 0; cchunk < 16; ++cchunk) {
                    q0 += ws[OFF_AAP + ((size_t)((0 * 16 + cchunk) * CC + j)) * CC + i];
                    q1 += ws[OFF_AAP + ((size_t)((1 * 16 + cchunk) * CC + j)) * CC + i];
                }
                const float mx = fmaxf(q0, q1);   // aa ~ O(4096): max-sub mandatory
                const float e0 = __expf(q0 - mx), e1 = __expf(q1 - mx);
                const float inv = 1.f / (e0 + e1);
                ws[OFF_XW + 0 * 1024 + i * 32 + j] = e0 * inv;
                ws[OFF_XW + 1 * 1024 + i * 32 + j] = e1 * inv;
            }
        }
    }
    gsync(cnt, 2 * NBLK);

    // ================= P2: Z[n] = sum_m exp(cb[m,n]-M[n]) =================
    {   // 512 blocks: b x ng(32, 128-wide n-strips) x mch(8, 512 m each)
        const ushort* fnc = (const ushort*)(ws + OFF_FNC);
        const int b = blk >> 8;
        const int rem = blk & 255;
        const int ng = rem >> 3, mch = rem & 7;
        const int nbA = ng * 128 + wv * 16, nbB = nbA + 64;
        const short8 bfA = *(const short8*)(fnc + ((size_t)(b * NN + nbA + ml)) * CC + kg * 8);
        const short8 bfB = *(const short8*)(fnc + ((size_t)(b * NN + nbB + ml)) * CC + kg * 8);
        const float MA = ws[OFF_M + b * NN + nbA + ml];
        const float MB = ws[OFF_M + b * NN + nbB + ml];
        float zA = 0.f, zB = 0.f;
        const int m0 = mch * 512;
        for (int mm = m0; mm < m0 + 512; mm += 16) {
            const short8 af = *(const short8*)(fnc + ((size_t)(b * NN + mm + ml)) * CC + kg * 8);
            f32x4 dA = __builtin_amdgcn_mfma_f32_16x16x32_bf16(af, bfA, fzero, 0, 0, 0);
            f32x4 dB = __builtin_amdgcn_mfma_f32_16x16x32_bf16(af, bfB, fzero, 0, 0, 0);
            zA += __expf(dA[0] - MA) + __expf(dA[1] - MA) + __expf(dA[2] - MA) + __expf(dA[3] - MA);
            zB += __expf(dB[0] - MB) + __expf(dB[1] - MB) + __expf(dB[2] - MB) + __expf(dB[3] - MB);
        }
        zA += __shfl_xor(zA, 16); zA += __shfl_xor(zA, 32);
        zB += __shfl_xor(zB, 16); zB += __shfl_xor(zB, 32);
        if (lane < 16) {
            atomicAdd(ws + OFF_Z + b * NN + nbA + ml, zA);
            atomicAdd(ws + OFF_Z + b * NN + nbB + ml, zB);
        }
    }
    gsync(cnt, 3 * NBLK);

    // ================= P3: e_p^T[c][m] += sum_n f[c,n] w[m,n] =================
    {   // 512 blocks: b x mg(64, 64-wide m) x nch(4, 1024 n each)
        const ushort* fnc = (const ushort*)(ws + OFF_FNC);
        const ushort* fcn = (const ushort*)(ws + OFF_FCN);
        const int b = blk >> 8;
        const int rem = blk & 255;
        const int mg = rem >> 2, nch = rem & 3;
        const int mb = mg * 64 + wv * 16;
        const short8 bm = *(const short8*)(fnc + ((size_t)(b * NN + mb + ml)) * CC + kg * 8);
        f32x4 acc0 = fzero, acc1 = fzero;         // e_p^T[c][m], c = kg*4+r (+16)
        const float* Mp = ws + OFF_M + b * NN;
        const float* Zp = ws + OFF_Z + b * NN;
        const int n0beg = nch * 1024;
        for (int n0 = n0beg; n0 < n0beg + 1024; n0 += 32) {
            // cb^T tiles: lane holds 4 n-rows (kg*4+r), col = ml (fixed m)
            const short8 an0 = *(const short8*)(fnc + ((size_t)(b * NN + n0      + ml)) * CC + kg * 8);
            const short8 an1 = *(const short8*)(fnc + ((size_t)(b * NN + n0 + 16 + ml)) * CC + kg * 8);
            f32x4 d0 = __builtin_amdgcn_mfma_f32_16x16x32_bf16(an0, bm, fzero, 0, 0, 0);
            f32x4 d1 = __builtin_amdgcn_mfma_f32_16x16x32_bf16(an1, bm, fzero, 0, 0, 0);
            const float4 M0 = *(const float4*)(Mp + n0 + kg * 4);
            const float4 M1 = *(const float4*)(Mp + n0 + 16 + kg * 4);
            const float4 Z0 = *(const float4*)(Zp + n0 + kg * 4);
            const float4 Z1 = *(const float4*)(Zp + n0 + 16 + kg * 4);
            const float w00 = __expf(d0[0] - M0.x) * __builtin_amdgcn_rcpf(Z0.x);
            const float w01 = __expf(d0[1] - M0.y) * __builtin_amdgcn_rcpf(Z0.y);
            const float w02 = __expf(d0[2] - M0.z) * __builtin_amdgcn_rcpf(Z0.z);
            const float w03 = __expf(d0[3] - M0.w) * __builtin_amdgcn_rcpf(Z0.w);
            const float w10 = __expf(d1[0] - M1.x) * __builtin_amdgcn_rcpf(Z1.x);
            const float w11 = __expf(d1[1] - M1.y) * __builtin_amdgcn_rcpf(Z1.y);
            const float w12 = __expf(d1[2] - M1.z) * __builtin_amdgcn_rcpf(Z1.z);
            const float w13 = __expf(d1[3] - M1.w) * __builtin_amdgcn_rcpf(Z1.w);
            // packed pairs along n, then 8-shfl redistribute into PV B-fragment
            const uint p0 = packbf(w00, w01), p1 = packbf(w02, w03);
            const uint q0 = packbf(w10, w11), q1 = packbf(w12, w13);
            union { uint u[4]; short8 s; } wf;
            {
                const int s0 = (((kg & 1) << 1) + 0) * 16 + ml;
                const int s1 = (((kg & 1) << 1) + 1) * 16 + ml;
                const uint vp0 = __shfl(p0, s0), vp1 = __shfl(p1, s0);
                const uint vp2 = __shfl(p0, s1), vp3 = __shfl(p1, s1);
                const uint vq0 = __shfl(q0, s0), vq1 = __shfl(q1, s0);
                const uint vq2 = __shfl(q0, s1), vq3 = __shfl(q1, s1);
                const bool hi = (kg >= 2);
                wf.u[0] = hi ? vq0 : vp0; wf.u[1] = hi ? vq1 : vp1;
                wf.u[2] = hi ? vq2 : vp2; wf.u[3] = hi ? vq3 : vp3;
            }
            const short8 a20 = *(const short8*)(fcn + ((size_t)(b * CC + ml))      * NN + n0 + kg * 8);
            const short8 a21 = *(const short8*)(fcn + ((size_t)(b * CC + 16 + ml)) * NN + n0 + kg * 8);
            acc0 = __builtin_amdgcn_mfma_f32_16x16x32_bf16(a20, wf.s, acc0, 0, 0, 0);
            acc1 = __builtin_amdgcn_mfma_f32_16x16x32_bf16(a21, wf.s, acc1, 0, 0, 0);
        }
        #pragma unroll
        for (int r = 0; r < 4; ++r) {
            atomicAdd(ws + OFF_EP + ((size_t)(b * CC + kg * 4 + r))      * NN + mb + ml, acc0[r]);
            atomicAdd(ws + OFF_EP + ((size_t)(b * CC + 16 + kg * 4 + r)) * NN + mb + ml, acc1[r]);
        }
    }
    gsync(cnt, 4 * NBLK);

    // ================= P4: out = alpha*e_p + beta*e_c + 2a =================
    {
        const float alpha = *alpha_p, beta = *beta_p;
        float* sa = smem;                          // [32 j][8 k]
        float* sxw = smem + 256;                   // [32 i][33] padded
        const int base = blk * 16;                 // 16 columns/block, same batch
        const int b = base >> 12;
        for (int li = t; li < CC * CC; li += 256)
            sxw[(li >> 5) * 33 + (li & 31)] = ws[OFF_XW + b * 1024 + li];
        const int k = t >> 5, c = t & 31;
        #pragma unroll
        for (int it = 0; it < 2; ++it) {
            const int m0 = (base + it * 8) & (NN - 1);
            __syncthreads();
            { const int j = t >> 3, kc = t & 7;
              sa[j * 8 + kc] = x[((size_t)(b * CC + j)) * NN + m0 + kc]; }
            __syncthreads();
            const int m = m0 + k;
            float ec = 0.f;
            #pragma unroll
            for (int j = 0; j < CC; ++j) ec += sxw[c * 33 + j] * sa[j * 8 + k];
            const float av = sa[c * 8 + k];
            const float ep = ws[OFF_EP + ((size_t)(b * CC + c)) * NN + m];
            out[((size_t)(b * CC + c)) * NN + m] = alpha * ep + beta * ec + 2.f * av;
        }
    }
}

extern "C" void kernel_launch(void* const* d_in, const int* in_sizes, int n_in,
                              void* d_out, int out_size, void* d_ws, size_t ws_size,
                              hipStream_t stream) {
    const float* x     = (const float*)d_in[0];
    const float* gamma = (const float*)d_in[1];
    const float* bias  = (const float*)d_in[2];
    const float* alpha = (const float*)d_in[3];
    const float* beta  = (const float*)d_in[4];
    float* out = (float*)d_out;
    float* ws  = (float*)d_ws;

    // zero the grid-barrier counter (ws is poisoned 0xAA before every launch)
    hipMemsetAsync((char*)d_ws + (size_t)OFF_CNT * 4, 0, 256, stream);

    hipLaunchKernelGGL(k_dam, dim3(NBLK), dim3(256), 0, stream,
                       x, gamma, bias, alpha, beta, ws, out);
}

// Round 6
// 135.376 us; speedup vs baseline: 3.6687x; 3.6687x over previous
//
#include <hip/hip_runtime.h>
#include <math.h>

// DAM (dual attention) on MI355X — 5-kernel chain (grid barriers proved 95us each
// in round 5; kernel boundaries are ~3us, so multi-kernel wins).
// B=2, C=32, N=4096, fp32 in/out; bf16 MFMA for the two N^2 passes.
//
// out = alpha*e_p + beta*e_c + 2*a
//   f = relu(BN(a));  cb[n,m] = sum_c f[c,n]f[c,m]
//   w[m,n] = exp(cb[m,n]-M[n]) / Z[n],  M[n]=cb[n,n] (shift-invariant stabilizer)
//   e_p[c,m] = sum_n f[c,n] w[m,n]
//   aa = a a^T (32x32 fp32), x = softmax over batch axis; e_c[i,n] = sum_j x[b,j,i] a[b,j,n]

#define BB 2
#define CC 32
#define NN 4096
#define EPSV 1e-5f

typedef short short8 __attribute__((ext_vector_type(8)));  // 8 bf16
typedef float f32x4 __attribute__((ext_vector_type(4)));

// ws float offsets
#define OFF_FNC  0          // bf16 f [B][N][C]      (131072 floats storage)
#define OFF_FCN  131072     // bf16 f [B][C][N]      (131072)
#define OFF_M    262144     // f32 M[b][n]           (8192)
#define OFF_SC   270336     // BN scale              (32)
#define OFF_SH   270368     // BN shift              (32)
#define OFF_XW   270400     // xw[b][i][j]=x[b,j,i]  (2048)
#define OFF_AAP  272448     // aa partials [b][16][32][32] (32768)
#define OFF_Z    305216     // f32 Z[b][n] atomic    (8192)
#define OFF_EP   313408     // f32 ep[b][c][n] atomic(262144)
#define ZERO_BASE 305216
#define ZERO_N4   67584     // (8192+262144)/4 float4s

__device__ inline ushort f2bf(float x) {            // RNE f32->bf16
    uint u = __float_as_uint(x);
    uint r = u + 0x7FFFu + ((u >> 16) & 1u);
    return (ushort)(r >> 16);
}
__device__ inline float bf2f(ushort h) { return __uint_as_float(((uint)h) << 16); }
__device__ inline uint packbf(float lo, float hi) { // truncating pack (w>=0)
    return (__float_as_uint(hi) & 0xFFFF0000u) | (__float_as_uint(lo) >> 16);
}

// ---------- K1: BN stats (blk 0-31) | aa partials (blk 32-95) | zero Z+EP ----------
__global__ void __launch_bounds__(256) k_pre(const float* __restrict__ x,
                                             const float* __restrict__ gamma,
                                             const float* __restrict__ bias,
                                             float* __restrict__ ws) {
    __shared__ float smem[4352];
    const int blk = blockIdx.x, t = threadIdx.x;
    const int lane = t & 63, wv = t >> 6;
    if (blk < 32) {
        const int c = blk;
        float s = 0.f, s2 = 0.f;
        for (int i = t; i < BB * NN; i += 256) {
            const int bb = i >> 12, n = i & (NN - 1);
            const float v = x[((size_t)(bb * CC + c)) * NN + n];
            s += v; s2 += v * v;
        }
        for (int off = 32; off; off >>= 1) { s += __shfl_down(s, off); s2 += __shfl_down(s2, off); }
        if (lane == 0) { smem[wv] = s; smem[4 + wv] = s2; }
        __syncthreads();
        if (t == 0) {
            const float S = smem[0] + smem[1] + smem[2] + smem[3];
            const float S2 = smem[4] + smem[5] + smem[6] + smem[7];
            const float mean = S * (1.f / (BB * NN));
            const float var = S2 * (1.f / (BB * NN)) - mean * mean;  // biased
            const float sc = gamma[c] * rsqrtf(var + EPSV);
            ws[OFF_SC + c] = sc;
            ws[OFF_SH + c] = bias[c] - mean * sc;
        }
    } else if (blk < 96) {
        // fp32 Gram partial over a 256-wide n-chunk (LDS tile, padded stride 132)
        const int blk2 = blk - 32;
        const int b = blk2 >> 4, chnk = blk2 & 15;
        const int nb = chnk * 256;
        const int d = t >> 3, cg4 = (t & 7) * 4;
        float a0 = 0.f, a1 = 0.f, a2 = 0.f, a3 = 0.f;
        for (int it = 0; it < 2; ++it) {
            __syncthreads();
            for (int li = t; li < 4096; li += 256) {
                const int row = li >> 7, col = li & 127;
                smem[row * 132 + col] = x[((size_t)(b * CC + row)) * NN + nb + it * 128 + col];
            }
            __syncthreads();
            for (int k = 0; k < 128; ++k) {
                const float vd = smem[d * 132 + k];
                a0 += smem[(cg4 + 0) * 132 + k] * vd;
                a1 += smem[(cg4 + 1) * 132 + k] * vd;
                a2 += smem[(cg4 + 2) * 132 + k] * vd;
                a3 += smem[(cg4 + 3) * 132 + k] * vd;
            }
        }
        float* dst = ws + OFF_AAP + ((size_t)((b * 16 + chnk) * CC + d)) * CC + cg4;
        dst[0] = a0; dst[1] = a1; dst[2] = a2; dst[3] = a3;
    } else {
        for (int gid = (blk - 96) * 256 + t; gid < ZERO_N4; gid += 416 * 256)
            ((float4*)(ws + ZERO_BASE))[gid] = make_float4(0.f, 0.f, 0.f, 0.f);
    }
}

// ---------- K2: f = relu(bn(x)) -> bf16 both layouts + M; blk 511 also xw ----------
__global__ void __launch_bounds__(256) k_makef(const float* __restrict__ x,
                                               float* __restrict__ ws) {
    const int blk = blockIdx.x, t = threadIdx.x;
    const int ch = t & 31;
    const float sc = ws[OFF_SC + ch], sh = ws[OFF_SH + ch];
    #pragma unroll
    for (int it = 0; it < 2; ++it) {
        const int col = (t >> 5) + it * 8;
        const int idx = blk * 16 + col;           // 8192 columns
        const int b = idx >> 12, n = idx & (NN - 1);
        const float v = x[((size_t)(b * CC + ch)) * NN + n];
        const float f = fmaxf(v * sc + sh, 0.f);
        const ushort h = f2bf(f);
        const float fr = bf2f(h);
        ((ushort*)(ws + OFF_FNC))[(size_t)idx * CC + ch] = h;
        ((ushort*)(ws + OFF_FCN))[((size_t)(b * CC + ch)) * NN + n] = h;
        float s = fr * fr;
        s += __shfl_xor(s, 1); s += __shfl_xor(s, 2); s += __shfl_xor(s, 4);
        s += __shfl_xor(s, 8); s += __shfl_xor(s, 16);
        if (ch == 0) ws[OFF_M + idx] = s;         // diag of bf16-cb, fp32 acc
    }
    if (blk == 511) {                             // CAM batch-axis softmax (aa from k_pre)
        for (int li = t; li < CC * CC; li += 256) {
            const int i = li >> 5, j = li & 31;
            float q0 = 0.f, q1 = 0.f;
            for (int cchunk = 0; cchunk < 16; ++cchunk) {
                q0 += ws[OFF_AAP + ((size_t)((0 * 16 + cchunk) * CC + j)) * CC + i];
                q1 += ws[OFF_AAP + ((size_t)((1 * 16 + cchunk) * CC + j)) * CC + i];
            }
            const float mx = fmaxf(q0, q1);       // aa ~ O(4096): max-sub mandatory
            const float e0 = __expf(q0 - mx), e1 = __expf(q1 - mx);
            const float inv = 1.f / (e0 + e1);
            ws[OFF_XW + 0 * 1024 + i * 32 + j] = e0 * inv;
            ws[OFF_XW + 1 * 1024 + i * 32 + j] = e1 * inv;
        }
    }
}

// ---------- K3: Z[n] = sum_m exp(cb[m,n]-M[n]);  1024 blocks, 4/CU ----------
__global__ void __launch_bounds__(256) k_zpass(float* __restrict__ ws) {
    const ushort* fnc = (const ushort*)(ws + OFF_FNC);
    const int blk = blockIdx.x, t = threadIdx.x;
    const int lane = t & 63, wv = t >> 6;
    const int ml = lane & 15, kg = lane >> 4;
    const f32x4 fzero = {0.f, 0.f, 0.f, 0.f};
    const int b = blk >> 9;
    const int rem = blk & 511;
    const int ng = rem >> 4;                      // 32 strips of 128 n
    const int mch = rem & 15;                     // 16 chunks of 256 m
    const int nbA = ng * 128 + wv * 16, nbB = nbA + 64;
    const short8 bfA = *(const short8*)(fnc + ((size_t)(b * NN + nbA + ml)) * CC + kg * 8);
    const short8 bfB = *(const short8*)(fnc + ((size_t)(b * NN + nbB + ml)) * CC + kg * 8);
    const float MA = ws[OFF_M + b * NN + nbA + ml];
    const float MB = ws[OFF_M + b * NN + nbB + ml];
    float zA = 0.f, zB = 0.f;
    const int m0 = mch * 256;
    for (int mm = m0; mm < m0 + 256; mm += 16) {
        const short8 af = *(const short8*)(fnc + ((size_t)(b * NN + mm + ml)) * CC + kg * 8);
        f32x4 dA = __builtin_amdgcn_mfma_f32_16x16x32_bf16(af, bfA, fzero, 0, 0, 0);
        f32x4 dB = __builtin_amdgcn_mfma_f32_16x16x32_bf16(af, bfB, fzero, 0, 0, 0);
        zA += __expf(dA[0] - MA) + __expf(dA[1] - MA) + __expf(dA[2] - MA) + __expf(dA[3] - MA);
        zB += __expf(dB[0] - MB) + __expf(dB[1] - MB) + __expf(dB[2] - MB) + __expf(dB[3] - MB);
    }
    zA += __shfl_xor(zA, 16); zA += __shfl_xor(zA, 32);
    zB += __shfl_xor(zB, 16); zB += __shfl_xor(zB, 32);
    if (lane < 16) {
        atomicAdd(ws + OFF_Z + b * NN + nbA + ml, zA);
        atomicAdd(ws + OFF_Z + b * NN + nbB + ml, zB);
    }
}

// ---------- K4: e_p^T[c][m] += sum_n f[c,n] w[m,n];  1024 blocks, rcp(Z) ----------
__global__ void __launch_bounds__(256) k_eppass(float* __restrict__ ws) {
    const ushort* fnc = (const ushort*)(ws + OFF_FNC);
    const ushort* fcn = (const ushort*)(ws + OFF_FCN);
    const int blk = blockIdx.x, t = threadIdx.x;
    const int lane = t & 63, wv = t >> 6;
    const int ml = lane & 15, kg = lane >> 4;
    const f32x4 fzero = {0.f, 0.f, 0.f, 0.f};
    const int b = blk >> 9;
    const int rem = blk & 511;
    const int mg = rem >> 3;                      // 64 groups of 64 m
    const int nch = rem & 7;                      // 8 chunks of 512 n
    const int mb = mg * 64 + wv * 16;
    const short8 bm = *(const short8*)(fnc + ((size_t)(b * NN + mb + ml)) * CC + kg * 8);
    f32x4 acc0 = fzero, acc1 = fzero;             // e_p^T[c][m], c = kg*4+r (+16)
    const float* Mp = ws + OFF_M + b * NN;
    const float* Zp = ws + OFF_Z + b * NN;
    const int n0beg = nch * 512;
    for (int n0 = n0beg; n0 < n0beg + 512; n0 += 32) {
        // cb^T tiles: lane holds 4 n-rows (kg*4+r), col = ml (fixed m)
        const short8 an0 = *(const short8*)(fnc + ((size_t)(b * NN + n0      + ml)) * CC + kg * 8);
        const short8 an1 = *(const short8*)(fnc + ((size_t)(b * NN + n0 + 16 + ml)) * CC + kg * 8);
        f32x4 d0 = __builtin_amdgcn_mfma_f32_16x16x32_bf16(an0, bm, fzero, 0, 0, 0);
        f32x4 d1 = __builtin_amdgcn_mfma_f32_16x16x32_bf16(an1, bm, fzero, 0, 0, 0);
        const float4 M0 = *(const float4*)(Mp + n0 + kg * 4);
        const float4 M1 = *(const float4*)(Mp + n0 + 16 + kg * 4);
        const float4 Z0 = *(const float4*)(Zp + n0 + kg * 4);
        const float4 Z1 = *(const float4*)(Zp + n0 + 16 + kg * 4);
        const float w00 = __expf(d0[0] - M0.x) * __builtin_amdgcn_rcpf(Z0.x);
        const float w01 = __expf(d0[1] - M0.y) * __builtin_amdgcn_rcpf(Z0.y);
        const float w02 = __expf(d0[2] - M0.z) * __builtin_amdgcn_rcpf(Z0.z);
        const float w03 = __expf(d0[3] - M0.w) * __builtin_amdgcn_rcpf(Z0.w);
        const float w10 = __expf(d1[0] - M1.x) * __builtin_amdgcn_rcpf(Z1.x);
        const float w11 = __expf(d1[1] - M1.y) * __builtin_amdgcn_rcpf(Z1.y);
        const float w12 = __expf(d1[2] - M1.z) * __builtin_amdgcn_rcpf(Z1.z);
        const float w13 = __expf(d1[3] - M1.w) * __builtin_amdgcn_rcpf(Z1.w);
        // packed pairs along n, then 8-shfl redistribute into PV B-fragment
        const uint p0 = packbf(w00, w01), p1 = packbf(w02, w03);
        const uint q0 = packbf(w10, w11), q1 = packbf(w12, w13);
        union { uint u[4]; short8 s; } wf;
        {
            const int s0 = (((kg & 1) << 1) + 0) * 16 + ml;
            const int s1 = (((kg & 1) << 1) + 1) * 16 + ml;
            const uint vp0 = __shfl(p0, s0), vp1 = __shfl(p1, s0);
            const uint vp2 = __shfl(p0, s1), vp3 = __shfl(p1, s1);
            const uint vq0 = __shfl(q0, s0), vq1 = __shfl(q1, s0);
            const uint vq2 = __shfl(q0, s1), vq3 = __shfl(q1, s1);
            const bool hi = (kg >= 2);
            wf.u[0] = hi ? vq0 : vp0; wf.u[1] = hi ? vq1 : vp1;
            wf.u[2] = hi ? vq2 : vp2; wf.u[3] = hi ? vq3 : vp3;
        }
        const short8 a20 = *(const short8*)(fcn + ((size_t)(b * CC + ml))      * NN + n0 + kg * 8);
        const short8 a21 = *(const short8*)(fcn + ((size_t)(b * CC + 16 + ml)) * NN + n0 + kg * 8);
        acc0 = __builtin_amdgcn_mfma_f32_16x16x32_bf16(a20, wf.s, acc0, 0, 0, 0);
        acc1 = __builtin_amdgcn_mfma_f32_16x16x32_bf16(a21, wf.s, acc1, 0, 0, 0);
    }
    #pragma unroll
    for (int r = 0; r < 4; ++r) {
        atomicAdd(ws + OFF_EP + ((size_t)(b * CC + kg * 4 + r))      * NN + mb + ml, acc0[r]);
        atomicAdd(ws + OFF_EP + ((size_t)(b * CC + 16 + kg * 4 + r)) * NN + mb + ml, acc1[r]);
    }
}

// ---------- K5: out = alpha*e_p + beta*e_c + 2a;  512 blocks ----------
__global__ void __launch_bounds__(256) k_final(const float* __restrict__ x,
                                               const float* __restrict__ alpha_p,
                                               const float* __restrict__ beta_p,
                                               const float* __restrict__ ws,
                                               float* __restrict__ out) {
    __shared__ float smem[1312];                   // sa 256 + sxw 1056
    const int blk = blockIdx.x, t = threadIdx.x;
    const float alpha = *alpha_p, beta = *beta_p;
    float* sa = smem;                              // [32 j][8 k]
    float* sxw = smem + 256;                       // [32 i][33] padded
    const int base = blk * 16;                     // 16 columns/block, same batch
    const int b = base >> 12;
    for (int li = t; li < CC * CC; li += 256)
        sxw[(li >> 5) * 33 + (li & 31)] = ws[OFF_XW + b * 1024 + li];
    const int k = t >> 5, c = t & 31;
    #pragma unroll
    for (int it = 0; it < 2; ++it) {
        const int m0 = (base + it * 8) & (NN - 1);
        __syncthreads();
        { const int j = t >> 3, kc = t & 7;
          sa[j * 8 + kc] = x[((size_t)(b * CC + j)) * NN + m0 + kc]; }
        __syncthreads();
        const int m = m0 + k;
        float ec = 0.f;
        #pragma unroll
        for (int j = 0; j < CC; ++j) ec += sxw[c * 33 + j] * sa[j * 8 + k];
        const float av = sa[c * 8 + k];
        const float ep = ws[OFF_EP + ((size_t)(b * CC + c)) * NN + m];
        out[((size_t)(b * CC + c)) * NN + m] = alpha * ep + beta * ec + 2.f * av;
    }
}

extern "C" void kernel_launch(void* const* d_in, const int* in_sizes, int n_in,
                              void* d_out, int out_size, void* d_ws, size_t ws_size,
                              hipStream_t stream) {
    const float* x     = (const float*)d_in[0];
    const float* gamma = (const float*)d_in[1];
    const float* bias  = (const float*)d_in[2];
    const float* alpha = (const float*)d_in[3];
    const float* beta  = (const float*)d_in[4];
    float* out = (float*)d_out;
    float* ws  = (float*)d_ws;

    hipLaunchKernelGGL(k_pre,    dim3(512),  dim3(256), 0, stream, x, gamma, bias, ws);
    hipLaunchKernelGGL(k_makef,  dim3(512),  dim3(256), 0, stream, x, ws);
    hipLaunchKernelGGL(k_zpass,  dim3(1024), dim3(256), 0, stream, ws);
    hipLaunchKernelGGL(k_eppass, dim3(1024), dim3(256), 0, stream, ws);
    hipLaunchKernelGGL(k_final,  dim3(512),  dim3(256), 0, stream, x, alpha, beta, ws, out);
}

// Round 8
// 129.060 us; speedup vs baseline: 3.8482x; 1.0489x over previous
//
#include <hip/hip_runtime.h>
#include <math.h>

// DAM (dual attention) on MI355X — 4-kernel chain.
// B=2, C=32, N=4096, fp32 in/out; bf16 MFMA for the two N^2 passes.
//
// out = alpha*e_p + beta*e_c + 2*a
//   f = relu(BN(a));  cb[n,m] = sum_c f[c,n]f[c,m]
//   w[m,n] = exp(cb[m,n]-M[n]) / Z[n],  M[n]=cb[n,n] (shift-invariant stabilizer)
//   e_p[c,m] = sum_n f[c,n] w[m,n]
//   aa = a a^T (32x32 fp32), x = softmax over batch axis; e_c[i,n] = sum_j x[b,j,i] a[b,j,n]
//
// K1 k_pre:     BN chunk-partials (256 blk) | aa partials (32 blk)
// K2 k_makef:   finalize BN, f -> bf16 both layouts, M, zero Z       (32 blk)
// K3 k_zpass:   Z[n] via MFMA cb tiles (2048 blk) + xw (1 blk)
// K4 k_epfinal: e_p via MFMA (8-way n-split per block, LDS-reduced) + epilogue (512 blk x 512 thr)

#define BB 2
#define CC 32
#define NN 4096
#define EPSV 1e-5f

typedef short short8 __attribute__((ext_vector_type(8)));  // 8 bf16
typedef float f32x4 __attribute__((ext_vector_type(4)));

// ws float offsets
#define OFF_FNC  0          // bf16 f [B][N][C]      (131072 floats storage)
#define OFF_FCN  131072     // bf16 f [B][C][N]      (131072)
#define OFF_M    262144     // f32 M[b][n]           (8192)
#define OFF_XW   270336     // xw[b][i][j]=x[b,j,i]  (2048)
#define OFF_AAP  272384     // aa partials [b][16][32][32] (32768)
#define OFF_S1P  305152     // BN sum partials [8][32]    (256)
#define OFF_S2P  305408     // BN sumsq partials [8][32]  (256)
#define OFF_Z    305664     // f32 Z[b][n] atomic    (8192, zeroed by k_makef)

__device__ inline ushort f2bf(float x) {            // RNE f32->bf16
    uint u = __float_as_uint(x);
    uint r = u + 0x7FFFu + ((u >> 16) & 1u);
    return (ushort)(r >> 16);
}
__device__ inline float bf2f(ushort h) { return __uint_as_float(((uint)h) << 16); }
__device__ inline uint packbf(float lo, float hi) { // truncating pack (w>=0)
    return (__float_as_uint(hi) & 0xFFFF0000u) | (__float_as_uint(lo) >> 16);
}

// ---------- K1: BN chunk-partials (blk 0-255) | aa partials (blk 256-287) ----------
__global__ void __launch_bounds__(256) k_pre(const float* __restrict__ x,
                                             float* __restrict__ ws) {
    __shared__ float smem[4352];
    const int blk = blockIdx.x, t = threadIdx.x;
    const int lane = t & 63, wv = t >> 6;
    if (blk < 256) {
        // channel c, 1024-element chunk of the flattened (b,n) axis; float4 coalesced
        const int c = blk & 31, chunk = blk >> 5;      // chunk in [0,8)
        const int i0 = chunk * 1024;
        const int b = i0 >> 12, n0 = i0 & (NN - 1);
        const float4 v = *(const float4*)(x + ((size_t)(b * CC + c)) * NN + n0 + t * 4);
        float s  = v.x + v.y + v.z + v.w;
        float s2 = v.x * v.x + v.y * v.y + v.z * v.z + v.w * v.w;
        for (int off = 32; off; off >>= 1) { s += __shfl_down(s, off); s2 += __shfl_down(s2, off); }
        if (lane == 0) { smem[wv] = s; smem[4 + wv] = s2; }
        __syncthreads();
        if (t == 0) {
            ws[OFF_S1P + chunk * 32 + c] = smem[0] + smem[1] + smem[2] + smem[3];
            ws[OFF_S2P + chunk * 32 + c] = smem[4] + smem[5] + smem[6] + smem[7];
        }
    } else {
        // fp32 Gram partial over a 256-wide n-chunk (32 blocks: b x 16 chunks)
        const int blk2 = blk - 256;                    // [0,32)
        const int b = blk2 >> 4, chnk = blk2 & 15;
        const int nb = chnk * 256;
        const int d = t >> 3, cg4 = (t & 7) * 4;
        float a0 = 0.f, a1 = 0.f, a2 = 0.f, a3 = 0.f;
        for (int it = 0; it < 2; ++it) {
            __syncthreads();
            for (int li = t; li < 4096; li += 256) {
                const int row = li >> 7, col = li & 127;
                smem[row * 132 + col] = x[((size_t)(b * CC + row)) * NN + nb + it * 128 + col];
            }
            __syncthreads();
            for (int k = 0; k < 128; ++k) {
                const float vd = smem[d * 132 + k];
                a0 += smem[(cg4 + 0) * 132 + k] * vd;
                a1 += smem[(cg4 + 1) * 132 + k] * vd;
                a2 += smem[(cg4 + 2) * 132 + k] * vd;
                a3 += smem[(cg4 + 3) * 132 + k] * vd;
            }
        }
        float* dst = ws + OFF_AAP + ((size_t)((b * 16 + chnk) * CC + d)) * CC + cg4;
        dst[0] = a0; dst[1] = a1; dst[2] = a2; dst[3] = a3;
    }
}

// ---------- K2: finalize BN; f = relu(bn(x)) -> bf16 both layouts + M; zero Z ----------
__global__ void __launch_bounds__(256) k_makef(const float* __restrict__ x,
                                               const float* __restrict__ gamma,
                                               const float* __restrict__ bias,
                                               float* __restrict__ ws) {
    __shared__ float ssc[CC], ssh[CC];
    const int blk = blockIdx.x, t = threadIdx.x;
    if (t < CC) {
        float S1 = 0.f, S2 = 0.f;
        #pragma unroll
        for (int k = 0; k < 8; ++k) { S1 += ws[OFF_S1P + k * 32 + t]; S2 += ws[OFF_S2P + k * 32 + t]; }
        const float mean = S1 * (1.f / (BB * NN));
        const float var = S2 * (1.f / (BB * NN)) - mean * mean;   // biased
        const float sc = gamma[t] * rsqrtf(var + EPSV);
        ssc[t] = sc; ssh[t] = bias[t] - mean * sc;
    }
    ws[OFF_Z + blk * 256 + t] = 0.f;            // zero Z for zpass atomics
    __syncthreads();
    const int idx = blk * 256 + t;              // n-column id, 8192 total
    const int b = idx >> 12, n = idx & (NN - 1);
    union { ushort us[CC]; short8 v[4]; } row;
    float msum = 0.f;
    #pragma unroll
    for (int c = 0; c < CC; ++c) {
        const float v = x[((size_t)(b * CC + c)) * NN + n];       // coalesced per c
        const float f = fmaxf(v * ssc[c] + ssh[c], 0.f);
        const ushort h = f2bf(f);
        const float fr = bf2f(h);
        msum += fr * fr;                        // diag of bf16-cb, fp32 acc
        row.us[c] = h;
        ((ushort*)(ws + OFF_FCN))[((size_t)(b * CC + c)) * NN + n] = h;  // coalesced
    }
    short8* dst = (short8*)((ushort*)(ws + OFF_FNC) + (size_t)idx * CC);
    dst[0] = row.v[0]; dst[1] = row.v[1]; dst[2] = row.v[2]; dst[3] = row.v[3];
    ws[OFF_M + idx] = msum;
}

// ---------- K3: Z[n] = sum_m exp(cb[m,n]-M[n]);  2048 blocks + xw block ----------
__global__ void __launch_bounds__(256) k_zpass(float* __restrict__ ws) {
    const int blk = blockIdx.x, t = threadIdx.x;
    if (blk == 2048) {                          // CAM batch-axis softmax (aa from k_pre)
        for (int li = t; li < CC * CC; li += 256) {
            const int i = li >> 5, j = li & 31;
            float q0 = 0.f, q1 = 0.f;
            for (int cchunk = 0; cchunk < 16; ++cchunk) {
                q0 += ws[OFF_AAP + ((size_t)((0 * 16 + cchunk) * CC + j)) * CC + i];
                q1 += ws[OFF_AAP + ((size_t)((1 * 16 + cchunk) * CC + j)) * CC + i];
            }
            const float mx = fmaxf(q0, q1);     // aa ~ O(4096): max-sub mandatory
            const float e0 = __expf(q0 - mx), e1 = __expf(q1 - mx);
            const float inv = 1.f / (e0 + e1);
            ws[OFF_XW + 0 * 1024 + i * 32 + j] = e0 * inv;
            ws[OFF_XW + 1 * 1024 + i * 32 + j] = e1 * inv;
        }
        return;
    }
    const ushort* fnc = (const ushort*)(ws + OFF_FNC);
    const int lane = t & 63, wv = t >> 6;
    const int ml = lane & 15, kg = lane >> 4;
    const f32x4 fzero = {0.f, 0.f, 0.f, 0.f};
    const int b = blk >> 10;
    const int rem = blk & 1023;
    const int ng = rem >> 5;                    // 32 strips of 128 n
    const int mch = rem & 31;                   // 32 chunks of 128 m
    const int nbA = ng * 128 + wv * 16, nbB = nbA + 64;
    const short8 bfA = *(const short8*)(fnc + ((size_t)(b * NN + nbA + ml)) * CC + kg * 8);
    const short8 bfB = *(const short8*)(fnc + ((size_t)(b * NN + nbB + ml)) * CC + kg * 8);
    const float MA = ws[OFF_M + b * NN + nbA + ml];
    const float MB = ws[OFF_M + b * NN + nbB + ml];
    float zA = 0.f, zB = 0.f;
    const int m0 = mch * 128;
    for (int mm = m0; mm < m0 + 128; mm += 16) {
        const short8 af = *(const short8*)(fnc + ((size_t)(b * NN + mm + ml)) * CC + kg * 8);
        f32x4 dA = __builtin_amdgcn_mfma_f32_16x16x32_bf16(af, bfA, fzero, 0, 0, 0);
        f32x4 dB = __builtin_amdgcn_mfma_f32_16x16x32_bf16(af, bfB, fzero, 0, 0, 0);
        zA += __expf(dA[0] - MA) + __expf(dA[1] - MA) + __expf(dA[2] - MA) + __expf(dA[3] - MA);
        zB += __expf(dB[0] - MB) + __expf(dB[1] - MB) + __expf(dB[2] - MB) + __expf(dB[3] - MB);
    }
    zA += __shfl_xor(zA, 16); zA += __shfl_xor(zA, 32);
    zB += __shfl_xor(zB, 16); zB += __shfl_xor(zB, 32);
    if (lane < 16) {
        atomicAdd(ws + OFF_Z + b * NN + nbA + ml, zA);
        atomicAdd(ws + OFF_Z + b * NN + nbB + ml, zB);
    }
}

// ---------- K4: e_p (8-way n-split, LDS reduce) + epilogue; 512 blk x 512 thr ----------
__global__ void __launch_bounds__(512) k_epfinal(const float* __restrict__ x,
                                                 const float* __restrict__ alpha_p,
                                                 const float* __restrict__ beta_p,
                                                 const float* __restrict__ ws,
                                                 float* __restrict__ out) {
    __shared__ float red[8][512];               // 16 KB: per-wave e_p^T partials
    __shared__ float sxw[CC * 33];              // padded
    __shared__ float sa[CC * 16];
    const ushort* fnc = (const ushort*)(ws + OFF_FNC);
    const ushort* fcn = (const ushort*)(ws + OFF_FCN);
    const int blk = blockIdx.x, t = threadIdx.x;
    const int lane = t & 63, wv = t >> 6;       // 8 waves
    const int ml = lane & 15, kg = lane >> 4;
    const f32x4 fzero = {0.f, 0.f, 0.f, 0.f};
    const int b = blk >> 8, mg = blk & 255;
    const int mb = mg * 16;                     // block's 16 output columns

    // stage epilogue inputs early (independent of main loop)
    { const int j = t >> 4, mcol = t & 15;
      sa[j * 16 + mcol] = x[((size_t)(b * CC + j)) * NN + mb + mcol]; }
    for (int li = t; li < CC * CC; li += 512)
        sxw[(li >> 5) * 33 + (li & 31)] = ws[OFF_XW + b * 1024 + li];

    // B-operand: cb^T cols = the block's 16 m (fixed for all waves)
    const short8 bm = *(const short8*)(fnc + ((size_t)(b * NN + mb + ml)) * CC + kg * 8);
    f32x4 acc0 = fzero, acc1 = fzero;           // e_p^T[c][m], c = kg*4+r (+16)
    const float* Mp = ws + OFF_M + b * NN;
    const float* Zp = ws + OFF_Z + b * NN;
    const int n0beg = wv * 512;                 // 8-way n-split across waves
    for (int n0 = n0beg; n0 < n0beg + 512; n0 += 32) {
        // cb^T tiles: lane holds 4 n-rows (kg*4+r), col = ml (fixed m)
        const short8 an0 = *(const short8*)(fnc + ((size_t)(b * NN + n0      + ml)) * CC + kg * 8);
        const short8 an1 = *(const short8*)(fnc + ((size_t)(b * NN + n0 + 16 + ml)) * CC + kg * 8);
        f32x4 d0 = __builtin_amdgcn_mfma_f32_16x16x32_bf16(an0, bm, fzero, 0, 0, 0);
        f32x4 d1 = __builtin_amdgcn_mfma_f32_16x16x32_bf16(an1, bm, fzero, 0, 0, 0);
        const float4 M0 = *(const float4*)(Mp + n0 + kg * 4);
        const float4 M1 = *(const float4*)(Mp + n0 + 16 + kg * 4);
        const float4 Z0 = *(const float4*)(Zp + n0 + kg * 4);
        const float4 Z1 = *(const float4*)(Zp + n0 + 16 + kg * 4);
        const float w00 = __expf(d0[0] - M0.x) * __builtin_amdgcn_rcpf(Z0.x);
        const float w01 = __expf(d0[1] - M0.y) * __builtin_amdgcn_rcpf(Z0.y);
        const float w02 = __expf(d0[2] - M0.z) * __builtin_amdgcn_rcpf(Z0.z);
        const float w03 = __expf(d0[3] - M0.w) * __builtin_amdgcn_rcpf(Z0.w);
        const float w10 = __expf(d1[0] - M1.x) * __builtin_amdgcn_rcpf(Z1.x);
        const float w11 = __expf(d1[1] - M1.y) * __builtin_amdgcn_rcpf(Z1.y);
        const float w12 = __expf(d1[2] - M1.z) * __builtin_amdgcn_rcpf(Z1.z);
        const float w13 = __expf(d1[3] - M1.w) * __builtin_amdgcn_rcpf(Z1.w);
        // packed pairs along n, then 8-shfl redistribute into PV B-fragment
        const uint p0 = packbf(w00, w01), p1 = packbf(w02, w03);
        const uint q0 = packbf(w10, w11), q1 = packbf(w12, w13);
        union { uint u[4]; short8 s; } wf;
        {
            const int s0 = (((kg & 1) << 1) + 0) * 16 + ml;
            const int s1 = (((kg & 1) << 1) + 1) * 16 + ml;
            const uint vp0 = __shfl(p0, s0), vp1 = __shfl(p1, s0);
            const uint vp2 = __shfl(p0, s1), vp3 = __shfl(p1, s1);
            const uint vq0 = __shfl(q0, s0), vq1 = __shfl(q1, s0);
            const uint vq2 = __shfl(q0, s1), vq3 = __shfl(q1, s1);
            const bool hi = (kg >= 2);
            wf.u[0] = hi ? vq0 : vp0; wf.u[1] = hi ? vq1 : vp1;
            wf.u[2] = hi ? vq2 : vp2; wf.u[3] = hi ? vq3 : vp3;
        }
        const short8 a20 = *(const short8*)(fcn + ((size_t)(b * CC + ml))      * NN + n0 + kg * 8);
        const short8 a21 = *(const short8*)(fcn + ((size_t)(b * CC + 16 + ml)) * NN + n0 + kg * 8);
        acc0 = __builtin_amdgcn_mfma_f32_16x16x32_bf16(a20, wf.s, acc0, 0, 0, 0);
        acc1 = __builtin_amdgcn_mfma_f32_16x16x32_bf16(a21, wf.s, acc1, 0, 0, 0);
    }
    #pragma unroll
    for (int r = 0; r < 4; ++r) {
        red[wv][(kg * 4 + r) * 16 + ml]      = acc0[r];
        red[wv][(16 + kg * 4 + r) * 16 + ml] = acc1[r];
    }
    __syncthreads();
    float ep = 0.f;
    #pragma unroll
    for (int w = 0; w < 8; ++w) ep += red[w][t];        // conflict-free (stride 512)
    const float alpha = *alpha_p, beta = *beta_p;
    const int c = t >> 4, m2 = t & 15;
    float ec = 0.f;
    #pragma unroll
    for (int j = 0; j < CC; ++j) ec += sxw[c * 33 + j] * sa[j * 16 + m2];
    const float av = sa[c * 16 + m2];
    out[((size_t)(b * CC + c)) * NN + mb + m2] = alpha * ep + beta * ec + 2.f * av;
}

extern "C" void kernel_launch(void* const* d_in, const int* in_sizes, int n_in,
                              void* d_out, int out_size, void* d_ws, size_t ws_size,
                              hipStream_t stream) {
    const float* x     = (const float*)d_in[0];
    const float* gamma = (const float*)d_in[1];
    const float* bias  = (const float*)d_in[2];
    const float* alpha = (const float*)d_in[3];
    const float* beta  = (const float*)d_in[4];
    float* out = (float*)d_out;
    float* ws  = (float*)d_ws;

    hipLaunchKernelGGL(k_pre,     dim3(288),  dim3(256), 0, stream, x, ws);
    hipLaunchKernelGGL(k_makef,   dim3(32),   dim3(256), 0, stream, x, gamma, bias, ws);
    hipLaunchKernelGGL(k_zpass,   dim3(2049), dim3(256), 0, stream, ws);
    hipLaunchKernelGGL(k_epfinal, dim3(512),  dim3(512), 0, stream, x, alpha, beta, ws, out);
}

// Round 9
// 124.821 us; speedup vs baseline: 3.9789x; 1.0340x over previous
//
#include <hip/hip_runtime.h>
#include <math.h>

// DAM (dual attention) on MI355X — 4-kernel chain, v2.
// B=2, C=32, N=4096, fp32 in/out; bf16 MFMA for the two N^2 passes.
//
// out = alpha*e_p + beta*e_c + 2*a
//   f = relu(BN(a));  cb[n,m] = sum_c f[c,n]f[c,m]
//   w[m,n] = exp(cb[m,n]-M[n]) / Z[n],  M[n]=cb[n,n] (shift-invariant stabilizer)
//   e_p[c,m] = sum_n f[c,n] w[m,n]
//   aa = a a^T (32x32 fp32), x = softmax over batch axis; e_c[i,n] = sum_j x[b,j,i] a[b,j,n]
//
// v2: FNC stores f*sqrt(log2e) so MFMA yields log2-domain logits -> exp2f.
//     FCN stays unscaled (PV operand). makef = 512 blocks, LDS transpose,
//     short8 stores. epfinal pre-inverts Z into LDS (no rcp in hot loop).

#define BB 2
#define CC 32
#define NN 4096
#define EPSV 1e-5f
#define SQL2E 1.2011224087864498f   // sqrt(log2(e))

typedef short short8 __attribute__((ext_vector_type(8)));  // 8 bf16
typedef float f32x4 __attribute__((ext_vector_type(4)));

// ws float offsets
#define OFF_FNC  0          // bf16 f*SQL2E [B][N][C]  (131072 floats storage)
#define OFF_FCN  131072     // bf16 f       [B][C][N]  (131072)
#define OFF_M    262144     // f32 M[b][n] scaled      (8192)
#define OFF_XW   270336     // xw[b][i][j]=x[b,j,i]    (2048)
#define OFF_AAP  272384     // aa partials [b][16][32][32] (32768)
#define OFF_S1P  305152     // BN sum partials [8][32]     (256)
#define OFF_S2P  305408     // BN sumsq partials [8][32]   (256)
#define OFF_Z    305664     // f32 Z[b][n] atomic      (8192, zeroed by k_makef)

__device__ inline ushort f2bf(float x) {            // RNE f32->bf16
    uint u = __float_as_uint(x);
    uint r = u + 0x7FFFu + ((u >> 16) & 1u);
    return (ushort)(r >> 16);
}
__device__ inline float bf2f(ushort h) { return __uint_as_float(((uint)h) << 16); }
__device__ inline uint packbf(float lo, float hi) { // truncating pack (w>=0)
    return (__float_as_uint(hi) & 0xFFFF0000u) | (__float_as_uint(lo) >> 16);
}

// ---------- K1: BN chunk-partials (blk 0-255) | aa partials (blk 256-287) ----------
__global__ void __launch_bounds__(256) k_pre(const float* __restrict__ x,
                                             float* __restrict__ ws) {
    __shared__ float smem[4352];
    const int blk = blockIdx.x, t = threadIdx.x;
    const int lane = t & 63, wv = t >> 6;
    if (blk < 256) {
        const int c = blk & 31, chunk = blk >> 5;      // chunk in [0,8)
        const int i0 = chunk * 1024;
        const int b = i0 >> 12, n0 = i0 & (NN - 1);
        const float4 v = *(const float4*)(x + ((size_t)(b * CC + c)) * NN + n0 + t * 4);
        float s  = v.x + v.y + v.z + v.w;
        float s2 = v.x * v.x + v.y * v.y + v.z * v.z + v.w * v.w;
        for (int off = 32; off; off >>= 1) { s += __shfl_down(s, off); s2 += __shfl_down(s2, off); }
        if (lane == 0) { smem[wv] = s; smem[4 + wv] = s2; }
        __syncthreads();
        if (t == 0) {
            ws[OFF_S1P + chunk * 32 + c] = smem[0] + smem[1] + smem[2] + smem[3];
            ws[OFF_S2P + chunk * 32 + c] = smem[4] + smem[5] + smem[6] + smem[7];
        }
    } else {
        // fp32 Gram partial over a 256-wide n-chunk (32 blocks: b x 16 chunks)
        const int blk2 = blk - 256;                    // [0,32)
        const int b = blk2 >> 4, chnk = blk2 & 15;
        const int nb = chnk * 256;
        const int d = t >> 3, cg4 = (t & 7) * 4;
        float a0 = 0.f, a1 = 0.f, a2 = 0.f, a3 = 0.f;
        for (int it = 0; it < 2; ++it) {
            __syncthreads();
            for (int li = t; li < 4096; li += 256) {
                const int row = li >> 7, col = li & 127;
                smem[row * 132 + col] = x[((size_t)(b * CC + row)) * NN + nb + it * 128 + col];
            }
            __syncthreads();
            for (int k = 0; k < 128; ++k) {
                const float vd = smem[d * 132 + k];
                a0 += smem[(cg4 + 0) * 132 + k] * vd;
                a1 += smem[(cg4 + 1) * 132 + k] * vd;
                a2 += smem[(cg4 + 2) * 132 + k] * vd;
                a3 += smem[(cg4 + 3) * 132 + k] * vd;
            }
        }
        float* dst = ws + OFF_AAP + ((size_t)((b * 16 + chnk) * CC + d)) * CC + cg4;
        dst[0] = a0; dst[1] = a1; dst[2] = a2; dst[3] = a3;
    }
}

// ---------- K2: finalize BN; f -> FCN (unscaled) + FNC (scaled, LDS transpose) + M; zero Z ----------
__global__ void __launch_bounds__(256) k_makef(const float* __restrict__ x,
                                               const float* __restrict__ gamma,
                                               const float* __restrict__ bias,
                                               float* __restrict__ ws) {
    __shared__ float ssc[CC], ssh[CC];
    __shared__ ushort tS[CC][18];               // scaled bf16, padded stride
    const int blk = blockIdx.x, t = threadIdx.x;
    const int base = blk * 16;                  // 16 columns, same batch
    const int b = base >> 12, n0 = base & (NN - 1);
    if (t < CC) {                               // redundant per-block finalize (cheap)
        float S1 = 0.f, S2 = 0.f;
        #pragma unroll
        for (int k = 0; k < 8; ++k) { S1 += ws[OFF_S1P + k * 32 + t]; S2 += ws[OFF_S2P + k * 32 + t]; }
        const float mean = S1 * (1.f / (BB * NN));
        const float var = S2 * (1.f / (BB * NN)) - mean * mean;   // biased
        const float sc = gamma[t] * rsqrtf(var + EPSV);
        ssc[t] = sc; ssh[t] = bias[t] - mean * sc;
    }
    __syncthreads();
    // phase A: thread (c = t>>3, cp = t&7) handles columns 2cp, 2cp+1
    {
        const int c = t >> 3, cp = t & 7;
        const float2 v = *(const float2*)(x + ((size_t)(b * CC + c)) * NN + n0 + 2 * cp);
        const float f0 = fmaxf(v.x * ssc[c] + ssh[c], 0.f);
        const float f1 = fmaxf(v.y * ssc[c] + ssh[c], 0.f);
        const ushort h0u = f2bf(f0), h1u = f2bf(f1);              // unscaled -> FCN
        ((uint*)((ushort*)(ws + OFF_FCN) + ((size_t)(b * CC + c)) * NN + n0))[cp] =
            (uint)h0u | ((uint)h1u << 16);
        const ushort h0s = f2bf(f0 * SQL2E), h1s = f2bf(f1 * SQL2E);  // scaled -> FNC
        tS[c][2 * cp]     = h0s;
        tS[c][2 * cp + 1] = h1s;
    }
    __syncthreads();
    // phase B: gather FNC rows (t<64), M (t in [64,80)), zero Z (t in [80,96))
    if (t < 64) {
        const int col = t >> 2, q = t & 3;
        union { ushort us[8]; short8 v; } r;
        #pragma unroll
        for (int j = 0; j < 8; ++j) r.us[j] = tS[q * 8 + j][col];
        *(short8*)((ushort*)(ws + OFF_FNC) + ((size_t)(base + col)) * CC + q * 8) = r.v;
    } else if (t < 80) {
        const int col = t - 64;
        float msum = 0.f;
        #pragma unroll
        for (int c = 0; c < CC; ++c) { const float fs = bf2f(tS[c][col]); msum += fs * fs; }
        ws[OFF_M + base + col] = msum;          // scaled diag = log2-domain stabilizer
    } else if (t < 96) {
        ws[OFF_Z + blk * 16 + (t - 80)] = 0.f;
    }
}

// ---------- K3: Z[n] = sum_m exp2(cb_s[m,n]-M[n]);  2048 blocks + xw block ----------
__global__ void __launch_bounds__(256) k_zpass(float* __restrict__ ws) {
    const int blk = blockIdx.x, t = threadIdx.x;
    if (blk == 2048) {                          // CAM batch-axis softmax (aa from k_pre)
        for (int li = t; li < CC * CC; li += 256) {
            const int i = li >> 5, j = li & 31;
            float q0 = 0.f, q1 = 0.f;
            for (int cchunk = 0; cchunk < 16; ++cchunk) {
                q0 += ws[OFF_AAP + ((size_t)((0 * 16 + cchunk) * CC + j)) * CC + i];
                q1 += ws[OFF_AAP + ((size_t)((1 * 16 + cchunk) * CC + j)) * CC + i];
            }
            const float mx = fmaxf(q0, q1);     // aa ~ O(4096): max-sub mandatory
            const float e0 = __expf(q0 - mx), e1 = __expf(q1 - mx);
            const float inv = 1.f / (e0 + e1);
            ws[OFF_XW + 0 * 1024 + i * 32 + j] = e0 * inv;
            ws[OFF_XW + 1 * 1024 + i * 32 + j] = e1 * inv;
        }
        return;
    }
    const ushort* fnc = (const ushort*)(ws + OFF_FNC);
    const int lane = t & 63, wv = t >> 6;
    const int ml = lane & 15, kg = lane >> 4;
    const f32x4 fzero = {0.f, 0.f, 0.f, 0.f};
    const int b = blk >> 10;
    const int rem = blk & 1023;
    const int ng = rem >> 5;                    // 32 strips of 128 n
    const int mch = rem & 31;                   // 32 chunks of 128 m
    const int nbA = ng * 128 + wv * 16, nbB = nbA + 64;
    const short8 bfA = *(const short8*)(fnc + ((size_t)(b * NN + nbA + ml)) * CC + kg * 8);
    const short8 bfB = *(const short8*)(fnc + ((size_t)(b * NN + nbB + ml)) * CC + kg * 8);
    const float MA = ws[OFF_M + b * NN + nbA + ml];
    const float MB = ws[OFF_M + b * NN + nbB + ml];
    float zA = 0.f, zB = 0.f;
    const int m0 = mch * 128;
    for (int mm = m0; mm < m0 + 128; mm += 16) {
        const short8 af = *(const short8*)(fnc + ((size_t)(b * NN + mm + ml)) * CC + kg * 8);
        f32x4 dA = __builtin_amdgcn_mfma_f32_16x16x32_bf16(af, bfA, fzero, 0, 0, 0);
        f32x4 dB = __builtin_amdgcn_mfma_f32_16x16x32_bf16(af, bfB, fzero, 0, 0, 0);
        zA += exp2f(dA[0] - MA) + exp2f(dA[1] - MA) + exp2f(dA[2] - MA) + exp2f(dA[3] - MA);
        zB += exp2f(dB[0] - MB) + exp2f(dB[1] - MB) + exp2f(dB[2] - MB) + exp2f(dB[3] - MB);
    }
    zA += __shfl_xor(zA, 16); zA += __shfl_xor(zA, 32);
    zB += __shfl_xor(zB, 16); zB += __shfl_xor(zB, 32);
    if (lane < 16) {
        atomicAdd(ws + OFF_Z + b * NN + nbA + ml, zA);
        atomicAdd(ws + OFF_Z + b * NN + nbB + ml, zB);
    }
}

// ---------- K4: e_p (8-way n-split, LDS reduce, LDS 1/Z) + epilogue; 512 blk x 512 thr ----------
__global__ void __launch_bounds__(512) k_epfinal(const float* __restrict__ x,
                                                 const float* __restrict__ alpha_p,
                                                 const float* __restrict__ beta_p,
                                                 const float* __restrict__ ws,
                                                 float* __restrict__ out) {
    __shared__ float red[8][512];               // 16 KB
    __shared__ float sM[NN];                    // 16 KB (scaled M)
    __shared__ float sZi[NN];                   // 16 KB (1/Z)
    __shared__ float sxw[CC * 33];              // padded
    __shared__ float sa[CC * 16];
    const ushort* fnc = (const ushort*)(ws + OFF_FNC);
    const ushort* fcn = (const ushort*)(ws + OFF_FCN);
    const int blk = blockIdx.x, t = threadIdx.x;
    const int lane = t & 63, wv = t >> 6;       // 8 waves
    const int ml = lane & 15, kg = lane >> 4;
    const f32x4 fzero = {0.f, 0.f, 0.f, 0.f};
    const int b = blk >> 8, mg = blk & 255;
    const int mb = mg * 16;                     // block's 16 output columns

    // pre-phase: invert Z into LDS, stage M, stage epilogue inputs
    {
        const float* Mp = ws + OFF_M + b * NN;
        const float* Zp = ws + OFF_Z + b * NN;
        #pragma unroll
        for (int i = t; i < NN / 4; i += 512) {
            const float4 z = *(const float4*)(Zp + i * 4);
            const float4 m = *(const float4*)(Mp + i * 4);
            ((float4*)sZi)[i] = make_float4(__builtin_amdgcn_rcpf(z.x), __builtin_amdgcn_rcpf(z.y),
                                            __builtin_amdgcn_rcpf(z.z), __builtin_amdgcn_rcpf(z.w));
            ((float4*)sM)[i] = m;
        }
        const int j = t >> 4, mcol = t & 15;
        sa[j * 16 + mcol] = x[((size_t)(b * CC + j)) * NN + mb + mcol];
        for (int li = t; li < CC * CC; li += 512)
            sxw[(li >> 5) * 33 + (li & 31)] = ws[OFF_XW + b * 1024 + li];
    }
    __syncthreads();

    // B-operand: cb^T cols = the block's 16 m (fixed for all waves)
    const short8 bm = *(const short8*)(fnc + ((size_t)(b * NN + mb + ml)) * CC + kg * 8);
    f32x4 acc0 = fzero, acc1 = fzero;           // e_p^T[c][m], c = kg*4+r (+16)
    const int n0beg = wv * 512;                 // 8-way n-split across waves
    for (int n0 = n0beg; n0 < n0beg + 512; n0 += 32) {
        // cb^T tiles: lane holds 4 n-rows (kg*4+r), col = ml (fixed m)
        const short8 an0 = *(const short8*)(fnc + ((size_t)(b * NN + n0      + ml)) * CC + kg * 8);
        const short8 an1 = *(const short8*)(fnc + ((size_t)(b * NN + n0 + 16 + ml)) * CC + kg * 8);
        f32x4 d0 = __builtin_amdgcn_mfma_f32_16x16x32_bf16(an0, bm, fzero, 0, 0, 0);
        f32x4 d1 = __builtin_amdgcn_mfma_f32_16x16x32_bf16(an1, bm, fzero, 0, 0, 0);
        const float4 M0 = *(const float4*)(sM + n0 + kg * 4);       // LDS broadcast
        const float4 M1 = *(const float4*)(sM + n0 + 16 + kg * 4);
        const float4 Z0 = *(const float4*)(sZi + n0 + kg * 4);
        const float4 Z1 = *(const float4*)(sZi + n0 + 16 + kg * 4);
        const float w00 = exp2f(d0[0] - M0.x) * Z0.x;
        const float w01 = exp2f(d0[1] - M0.y) * Z0.y;
        const float w02 = exp2f(d0[2] - M0.z) * Z0.z;
        const float w03 = exp2f(d0[3] - M0.w) * Z0.w;
        const float w10 = exp2f(d1[0] - M1.x) * Z1.x;
        const float w11 = exp2f(d1[1] - M1.y) * Z1.y;
        const float w12 = exp2f(d1[2] - M1.z) * Z1.z;
        const float w13 = exp2f(d1[3] - M1.w) * Z1.w;
        // packed pairs along n, then 8-shfl redistribute into PV B-fragment
        const uint p0 = packbf(w00, w01), p1 = packbf(w02, w03);
        const uint q0 = packbf(w10, w11), q1 = packbf(w12, w13);
        union { uint u[4]; short8 s; } wf;
        {
            const int s0 = (((kg & 1) << 1) + 0) * 16 + ml;
            const int s1 = (((kg & 1) << 1) + 1) * 16 + ml;
            const uint vp0 = __shfl(p0, s0), vp1 = __shfl(p1, s0);
            const uint vp2 = __shfl(p0, s1), vp3 = __shfl(p1, s1);
            const uint vq0 = __shfl(q0, s0), vq1 = __shfl(q1, s0);
            const uint vq2 = __shfl(q0, s1), vq3 = __shfl(q1, s1);
            const bool hi = (kg >= 2);
            wf.u[0] = hi ? vq0 : vp0; wf.u[1] = hi ? vq1 : vp1;
            wf.u[2] = hi ? vq2 : vp2; wf.u[3] = hi ? vq3 : vp3;
        }
        const short8 a20 = *(const short8*)(fcn + ((size_t)(b * CC + ml))      * NN + n0 + kg * 8);
        const short8 a21 = *(const short8*)(fcn + ((size_t)(b * CC + 16 + ml)) * NN + n0 + kg * 8);
        acc0 = __builtin_amdgcn_mfma_f32_16x16x32_bf16(a20, wf.s, acc0, 0, 0, 0);
        acc1 = __builtin_amdgcn_mfma_f32_16x16x32_bf16(a21, wf.s, acc1, 0, 0, 0);
    }
    #pragma unroll
    for (int r = 0; r < 4; ++r) {
        red[wv][(kg * 4 + r) * 16 + ml]      = acc0[r];
        red[wv][(16 + kg * 4 + r) * 16 + ml] = acc1[r];
    }
    __syncthreads();
    float ep = 0.f;
    #pragma unroll
    for (int w = 0; w < 8; ++w) ep += red[w][t];        // conflict-free (stride 512)
    const float alpha = *alpha_p, beta = *beta_p;
    const int c = t >> 4, m2 = t & 15;
    float ec = 0.f;
    #pragma unroll
    for (int j = 0; j < CC; ++j) ec += sxw[c * 33 + j] * sa[j * 16 + m2];
    const float av = sa[c * 16 + m2];
    out[((size_t)(b * CC + c)) * NN + mb + m2] = alpha * ep + beta * ec + 2.f * av;
}

extern "C" void kernel_launch(void* const* d_in, const int* in_sizes, int n_in,
                              void* d_out, int out_size, void* d_ws, size_t ws_size,
                              hipStream_t stream) {
    const float* x     = (const float*)d_in[0];
    const float* gamma = (const float*)d_in[1];
    const float* bias  = (const float*)d_in[2];
    const float* alpha = (const float*)d_in[3];
    const float* beta  = (const float*)d_in[4];
    float* out = (float*)d_out;
    float* ws  = (float*)d_ws;

    hipLaunchKernelGGL(k_pre,     dim3(288),  dim3(256), 0, stream, x, ws);
    hipLaunchKernelGGL(k_makef,   dim3(512),  dim3(256), 0, stream, x, gamma, bias, ws);
    hipLaunchKernelGGL(k_zpass,   dim3(2049), dim3(256), 0, stream, ws);
    hipLaunchKernelGGL(k_epfinal, dim3(512),  dim3(512), 0, stream, x, alpha, beta, ws, out);
}

// Round 10
// 120.552 us; speedup vs baseline: 4.1199x; 1.0354x over previous
//
#include <hip/hip_runtime.h>
#include <math.h>

// DAM (dual attention) on MI355X — 4-kernel chain, v3.
// B=2, C=32, N=4096, fp32 in/out; bf16 MFMA for the two N^2 passes.
//
// out = alpha*e_p + beta*e_c + 2*a
//   f = relu(BN(a));  cb[n,m] = sum_c f[c,n]f[c,m]
//   w[m,n] = exp(cb[m,n]-M[n]) / Z[n],  M[n]=cb[n,n] (shift-invariant stabilizer)
//   e_p[c,m] = sum_n f[c,n] w[m,n]
//   aa = a a^T (32x32 fp32), x = softmax over batch axis; e_c[i,n] = sum_j x[b,j,i] a[b,j,n]
//
// v3: k_pre = BN partials only (256 blk). aa-Gram moved into makef's spare
//     blocks (runs concurrent). zpass back to 1024 blocks (256-m chunks).
//     FNC stores f*sqrt(log2e) -> exp2f path. epfinal: LDS 1/Z + M staging.

#define BB 2
#define CC 32
#define NN 4096
#define EPSV 1e-5f
#define SQL2E 1.2011224087864498f   // sqrt(log2(e))

typedef short short8 __attribute__((ext_vector_type(8)));  // 8 bf16
typedef float f32x4 __attribute__((ext_vector_type(4)));

// ws float offsets
#define OFF_FNC  0          // bf16 f*SQL2E [B][N][C]  (131072 floats storage)
#define OFF_FCN  131072     // bf16 f       [B][C][N]  (131072)
#define OFF_M    262144     // f32 M[b][n] scaled      (8192)
#define OFF_XW   270336     // xw[b][i][j]=x[b,j,i]    (2048)
#define OFF_AAP  272384     // aa partials [b][16][32][32] (32768)
#define OFF_S1P  305152     // BN sum partials [8][32]     (256)
#define OFF_S2P  305408     // BN sumsq partials [8][32]   (256)
#define OFF_Z    305664     // f32 Z[b][n] atomic      (8192, zeroed by k_makef)

__device__ inline ushort f2bf(float x) {            // RNE f32->bf16
    uint u = __float_as_uint(x);
    uint r = u + 0x7FFFu + ((u >> 16) & 1u);
    return (ushort)(r >> 16);
}
__device__ inline float bf2f(ushort h) { return __uint_as_float(((uint)h) << 16); }
__device__ inline uint packbf(float lo, float hi) { // truncating pack (w>=0)
    return (__float_as_uint(hi) & 0xFFFF0000u) | (__float_as_uint(lo) >> 16);
}

// ---------- K1: BN chunk-partials only (256 blocks) ----------
__global__ void __launch_bounds__(256) k_pre(const float* __restrict__ x,
                                             float* __restrict__ ws) {
    __shared__ float smem[8];
    const int blk = blockIdx.x, t = threadIdx.x;
    const int lane = t & 63, wv = t >> 6;
    const int c = blk & 31, chunk = blk >> 5;       // chunk in [0,8)
    const int i0 = chunk * 1024;
    const int b = i0 >> 12, n0 = i0 & (NN - 1);
    const float4 v = *(const float4*)(x + ((size_t)(b * CC + c)) * NN + n0 + t * 4);
    float s  = v.x + v.y + v.z + v.w;
    float s2 = v.x * v.x + v.y * v.y + v.z * v.z + v.w * v.w;
    for (int off = 32; off; off >>= 1) { s += __shfl_down(s, off); s2 += __shfl_down(s2, off); }
    if (lane == 0) { smem[wv] = s; smem[4 + wv] = s2; }
    __syncthreads();
    if (t == 0) {
        ws[OFF_S1P + chunk * 32 + c] = smem[0] + smem[1] + smem[2] + smem[3];
        ws[OFF_S2P + chunk * 32 + c] = smem[4] + smem[5] + smem[6] + smem[7];
    }
}

// ---------- K2: finalize BN; f -> FCN + FNC + M; zero Z | aa partials (blk 512-543) ----------
__global__ void __launch_bounds__(256) k_makef(const float* __restrict__ x,
                                               const float* __restrict__ gamma,
                                               const float* __restrict__ bias,
                                               float* __restrict__ ws) {
    __shared__ float smem[4352];                // aa tile 32x132 | {ssc,ssh,tS}
    const int blk = blockIdx.x, t = threadIdx.x;
    if (blk >= 512) {
        // fp32 Gram partial over a 256-wide n-chunk (32 blocks: b x 16 chunks)
        const int blk2 = blk - 512;             // [0,32)
        const int b = blk2 >> 4, chnk = blk2 & 15;
        const int nb = chnk * 256;
        const int d = t >> 3, cg4 = (t & 7) * 4;
        float a0 = 0.f, a1 = 0.f, a2 = 0.f, a3 = 0.f;
        for (int it = 0; it < 2; ++it) {
            __syncthreads();
            for (int li = t; li < 4096; li += 256) {
                const int row = li >> 7, col = li & 127;
                smem[row * 132 + col] = x[((size_t)(b * CC + row)) * NN + nb + it * 128 + col];
            }
            __syncthreads();
            for (int k = 0; k < 128; ++k) {
                const float vd = smem[d * 132 + k];
                a0 += smem[(cg4 + 0) * 132 + k] * vd;
                a1 += smem[(cg4 + 1) * 132 + k] * vd;
                a2 += smem[(cg4 + 2) * 132 + k] * vd;
                a3 += smem[(cg4 + 3) * 132 + k] * vd;
            }
        }
        float* dst = ws + OFF_AAP + ((size_t)((b * 16 + chnk) * CC + d)) * CC + cg4;
        dst[0] = a0; dst[1] = a1; dst[2] = a2; dst[3] = a3;
        return;
    }
    float* ssc = smem;                          // [32]
    float* ssh = smem + 32;                     // [32]
    ushort* tS = (ushort*)(smem + 64);          // [32][18] scaled bf16, padded
    const int base = blk * 16;                  // 16 columns, same batch
    const int b = base >> 12, n0 = base & (NN - 1);
    if (t < CC) {                               // redundant per-block finalize (cheap)
        float S1 = 0.f, S2 = 0.f;
        #pragma unroll
        for (int k = 0; k < 8; ++k) { S1 += ws[OFF_S1P + k * 32 + t]; S2 += ws[OFF_S2P + k * 32 + t]; }
        const float mean = S1 * (1.f / (BB * NN));
        const float var = S2 * (1.f / (BB * NN)) - mean * mean;   // biased
        const float sc = gamma[t] * rsqrtf(var + EPSV);
        ssc[t] = sc; ssh[t] = bias[t] - mean * sc;
    }
    __syncthreads();
    // phase A: thread (c = t>>3, cp = t&7) handles columns 2cp, 2cp+1
    {
        const int c = t >> 3, cp = t & 7;
        const float2 v = *(const float2*)(x + ((size_t)(b * CC + c)) * NN + n0 + 2 * cp);
        const float f0 = fmaxf(v.x * ssc[c] + ssh[c], 0.f);
        const float f1 = fmaxf(v.y * ssc[c] + ssh[c], 0.f);
        const ushort h0u = f2bf(f0), h1u = f2bf(f1);              // unscaled -> FCN
        ((uint*)((ushort*)(ws + OFF_FCN) + ((size_t)(b * CC + c)) * NN + n0))[cp] =
            (uint)h0u | ((uint)h1u << 16);
        const ushort h0s = f2bf(f0 * SQL2E), h1s = f2bf(f1 * SQL2E);  // scaled -> FNC
        tS[c * 18 + 2 * cp]     = h0s;
        tS[c * 18 + 2 * cp + 1] = h1s;
    }
    __syncthreads();
    // phase B: gather FNC rows (t<64), M (t in [64,80)), zero Z (t in [80,96))
    if (t < 64) {
        const int col = t >> 2, q = t & 3;
        union { ushort us[8]; short8 v; } r;
        #pragma unroll
        for (int j = 0; j < 8; ++j) r.us[j] = tS[(q * 8 + j) * 18 + col];
        *(short8*)((ushort*)(ws + OFF_FNC) + ((size_t)(base + col)) * CC + q * 8) = r.v;
    } else if (t < 80) {
        const int col = t - 64;
        float msum = 0.f;
        #pragma unroll
        for (int c = 0; c < CC; ++c) { const float fs = bf2f(tS[c * 18 + col]); msum += fs * fs; }
        ws[OFF_M + base + col] = msum;          // scaled diag = log2-domain stabilizer
    } else if (t < 96) {
        ws[OFF_Z + blk * 16 + (t - 80)] = 0.f;
    }
}

// ---------- K3: Z[n] = sum_m exp2(cb_s[m,n]-M[n]);  1024 blocks + xw block ----------
__global__ void __launch_bounds__(256) k_zpass(float* __restrict__ ws) {
    const int blk = blockIdx.x, t = threadIdx.x;
    if (blk == 1024) {                          // CAM batch-axis softmax (aa from makef)
        for (int li = t; li < CC * CC; li += 256) {
            const int i = li >> 5, j = li & 31;
            float q0 = 0.f, q1 = 0.f;
            for (int cchunk = 0; cchunk < 16; ++cchunk) {
                q0 += ws[OFF_AAP + ((size_t)((0 * 16 + cchunk) * CC + j)) * CC + i];
                q1 += ws[OFF_AAP + ((size_t)((1 * 16 + cchunk) * CC + j)) * CC + i];
            }
            const float mx = fmaxf(q0, q1);     // aa ~ O(4096): max-sub mandatory
            const float e0 = __expf(q0 - mx), e1 = __expf(q1 - mx);
            const float inv = 1.f / (e0 + e1);
            ws[OFF_XW + 0 * 1024 + i * 32 + j] = e0 * inv;
            ws[OFF_XW + 1 * 1024 + i * 32 + j] = e1 * inv;
        }
        return;
    }
    const ushort* fnc = (const ushort*)(ws + OFF_FNC);
    const int lane = t & 63, wv = t >> 6;
    const int ml = lane & 15, kg = lane >> 4;
    const f32x4 fzero = {0.f, 0.f, 0.f, 0.f};
    const int b = blk >> 9;
    const int rem = blk & 511;
    const int ng = rem >> 4;                    // 32 strips of 128 n
    const int mch = rem & 15;                   // 16 chunks of 256 m
    const int nbA = ng * 128 + wv * 16, nbB = nbA + 64;
    const short8 bfA = *(const short8*)(fnc + ((size_t)(b * NN + nbA + ml)) * CC + kg * 8);
    const short8 bfB = *(const short8*)(fnc + ((size_t)(b * NN + nbB + ml)) * CC + kg * 8);
    const float MA = ws[OFF_M + b * NN + nbA + ml];
    const float MB = ws[OFF_M + b * NN + nbB + ml];
    float zA = 0.f, zB = 0.f;
    const int m0 = mch * 256;
    for (int mm = m0; mm < m0 + 256; mm += 16) {
        const short8 af = *(const short8*)(fnc + ((size_t)(b * NN + mm + ml)) * CC + kg * 8);
        f32x4 dA = __builtin_amdgcn_mfma_f32_16x16x32_bf16(af, bfA, fzero, 0, 0, 0);
        f32x4 dB = __builtin_amdgcn_mfma_f32_16x16x32_bf16(af, bfB, fzero, 0, 0, 0);
        zA += exp2f(dA[0] - MA) + exp2f(dA[1] - MA) + exp2f(dA[2] - MA) + exp2f(dA[3] - MA);
        zB += exp2f(dB[0] - MB) + exp2f(dB[1] - MB) + exp2f(dB[2] - MB) + exp2f(dB[3] - MB);
    }
    zA += __shfl_xor(zA, 16); zA += __shfl_xor(zA, 32);
    zB += __shfl_xor(zB, 16); zB += __shfl_xor(zB, 32);
    if (lane < 16) {
        atomicAdd(ws + OFF_Z + b * NN + nbA + ml, zA);
        atomicAdd(ws + OFF_Z + b * NN + nbB + ml, zB);
    }
}

// ---------- K4: e_p (8-way n-split, LDS reduce, LDS 1/Z) + epilogue; 512 blk x 512 thr ----------
__global__ void __launch_bounds__(512) k_epfinal(const float* __restrict__ x,
                                                 const float* __restrict__ alpha_p,
                                                 const float* __restrict__ beta_p,
                                                 const float* __restrict__ ws,
                                                 float* __restrict__ out) {
    __shared__ float red[8][512];               // 16 KB
    __shared__ float sM[NN];                    // 16 KB (scaled M)
    __shared__ float sZi[NN];                   // 16 KB (1/Z)
    __shared__ float sxw[CC * 33];              // padded
    __shared__ float sa[CC * 16];
    const ushort* fnc = (const ushort*)(ws + OFF_FNC);
    const ushort* fcn = (const ushort*)(ws + OFF_FCN);
    const int blk = blockIdx.x, t = threadIdx.x;
    const int lane = t & 63, wv = t >> 6;       // 8 waves
    const int ml = lane & 15, kg = lane >> 4;
    const f32x4 fzero = {0.f, 0.f, 0.f, 0.f};
    const int b = blk >> 8, mg = blk & 255;
    const int mb = mg * 16;                     // block's 16 output columns

    // pre-phase: invert Z into LDS, stage M, stage epilogue inputs
    {
        const float* Mp = ws + OFF_M + b * NN;
        const float* Zp = ws + OFF_Z + b * NN;
        #pragma unroll
        for (int i = t; i < NN / 4; i += 512) {
            const float4 z = *(const float4*)(Zp + i * 4);
            const float4 m = *(const float4*)(Mp + i * 4);
            ((float4*)sZi)[i] = make_float4(__builtin_amdgcn_rcpf(z.x), __builtin_amdgcn_rcpf(z.y),
                                            __builtin_amdgcn_rcpf(z.z), __builtin_amdgcn_rcpf(z.w));
            ((float4*)sM)[i] = m;
        }
        const int j = t >> 4, mcol = t & 15;
        sa[j * 16 + mcol] = x[((size_t)(b * CC + j)) * NN + mb + mcol];
        for (int li = t; li < CC * CC; li += 512)
            sxw[(li >> 5) * 33 + (li & 31)] = ws[OFF_XW + b * 1024 + li];
    }
    __syncthreads();

    // B-operand: cb^T cols = the block's 16 m (fixed for all waves)
    const short8 bm = *(const short8*)(fnc + ((size_t)(b * NN + mb + ml)) * CC + kg * 8);
    f32x4 acc0 = fzero, acc1 = fzero;           // e_p^T[c][m], c = kg*4+r (+16)
    const int n0beg = wv * 512;                 // 8-way n-split across waves
    for (int n0 = n0beg; n0 < n0beg + 512; n0 += 32) {
        // cb^T tiles: lane holds 4 n-rows (kg*4+r), col = ml (fixed m)
        const short8 an0 = *(const short8*)(fnc + ((size_t)(b * NN + n0      + ml)) * CC + kg * 8);
        const short8 an1 = *(const short8*)(fnc + ((size_t)(b * NN + n0 + 16 + ml)) * CC + kg * 8);
        f32x4 d0 = __builtin_amdgcn_mfma_f32_16x16x32_bf16(an0, bm, fzero, 0, 0, 0);
        f32x4 d1 = __builtin_amdgcn_mfma_f32_16x16x32_bf16(an1, bm, fzero, 0, 0, 0);
        const float4 M0 = *(const float4*)(sM + n0 + kg * 4);       // LDS broadcast
        const float4 M1 = *(const float4*)(sM + n0 + 16 + kg * 4);
        const float4 Z0 = *(const float4*)(sZi + n0 + kg * 4);
        const float4 Z1 = *(const float4*)(sZi + n0 + 16 + kg * 4);
        const float w00 = exp2f(d0[0] - M0.x) * Z0.x;
        const float w01 = exp2f(d0[1] - M0.y) * Z0.y;
        const float w02 = exp2f(d0[2] - M0.z) * Z0.z;
        const float w03 = exp2f(d0[3] - M0.w) * Z0.w;
        const float w10 = exp2f(d1[0] - M1.x) * Z1.x;
        const float w11 = exp2f(d1[1] - M1.y) * Z1.y;
        const float w12 = exp2f(d1[2] - M1.z) * Z1.z;
        const float w13 = exp2f(d1[3] - M1.w) * Z1.w;
        // packed pairs along n, then 8-shfl redistribute into PV B-fragment
        const uint p0 = packbf(w00, w01), p1 = packbf(w02, w03);
        const uint q0 = packbf(w10, w11), q1 = packbf(w12, w13);
        union { uint u[4]; short8 s; } wf;
        {
            const int s0 = (((kg & 1) << 1) + 0) * 16 + ml;
            const int s1 = (((kg & 1) << 1) + 1) * 16 + ml;
            const uint vp0 = __shfl(p0, s0), vp1 = __shfl(p1, s0);
            const uint vp2 = __shfl(p0, s1), vp3 = __shfl(p1, s1);
            const uint vq0 = __shfl(q0, s0), vq1 = __shfl(q1, s0);
            const uint vq2 = __shfl(q0, s1), vq3 = __shfl(q1, s1);
            const bool hi = (kg >= 2);
            wf.u[0] = hi ? vq0 : vp0; wf.u[1] = hi ? vq1 : vp1;
            wf.u[2] = hi ? vq2 : vp2; wf.u[3] = hi ? vq3 : vp3;
        }
        const short8 a20 = *(const short8*)(fcn + ((size_t)(b * CC + ml))      * NN + n0 + kg * 8);
        const short8 a21 = *(const short8*)(fcn + ((size_t)(b * CC + 16 + ml)) * NN + n0 + kg * 8);
        acc0 = __builtin_amdgcn_mfma_f32_16x16x32_bf16(a20, wf.s, acc0, 0, 0, 0);
        acc1 = __builtin_amdgcn_mfma_f32_16x16x32_bf16(a21, wf.s, acc1, 0, 0, 0);
    }
    #pragma unroll
    for (int r = 0; r < 4; ++r) {
        red[wv][(kg * 4 + r) * 16 + ml]      = acc0[r];
        red[wv][(16 + kg * 4 + r) * 16 + ml] = acc1[r];
    }
    __syncthreads();
    float ep = 0.f;
    #pragma unroll
    for (int w = 0; w < 8; ++w) ep += red[w][t];        // conflict-free (stride 512)
    const float alpha = *alpha_p, beta = *beta_p;
    const int c = t >> 4, m2 = t & 15;
    float ec = 0.f;
    #pragma unroll
    for (int j = 0; j < CC; ++j) ec += sxw[c * 33 + j] * sa[j * 16 + m2];
    const float av = sa[c * 16 + m2];
    out[((size_t)(b * CC + c)) * NN + mb + m2] = alpha * ep + beta * ec + 2.f * av;
}

extern "C" void kernel_launch(void* const* d_in, const int* in_sizes, int n_in,
                              void* d_out, int out_size, void* d_ws, size_t ws_size,
                              hipStream_t stream) {
    const float* x     = (const float*)d_in[0];
    const float* gamma = (const float*)d_in[1];
    const float* bias  = (const float*)d_in[2];
    const float* alpha = (const float*)d_in[3];
    const float* beta  = (const float*)d_in[4];
    float* out = (float*)d_out;
    float* ws  = (float*)d_ws;

    hipLaunchKernelGGL(k_pre,     dim3(256),  dim3(256), 0, stream, x, ws);
    hipLaunchKernelGGL(k_makef,   dim3(544),  dim3(256), 0, stream, x, gamma, bias, ws);
    hipLaunchKernelGGL(k_zpass,   dim3(1025), dim3(256), 0, stream, ws);
    hipLaunchKernelGGL(k_epfinal, dim3(512),  dim3(512), 0, stream, x, alpha, beta, ws, out);
}